// Round 6
// baseline (292.379 us; speedup 1.0000x reference)
//
#include <hip/hip_runtime.h>
#include <cstdint>
#include <cstddef>

// ---- problem constants ----
#define NBATCH   16384
#define NSEC     9
#define NOC      50        // conv output channels per section
#define NOCP     64        // padded to 4 MFMA n-tiles
#define KPAD     256       // padded K (zero pad 240..255 in wks)
#define KREAL    240
#define XROW     1640      // 41*40 floats per batch
#define TB       16        // batches per block (MFMA m)
#define WELEMS   147456    // 9*64*256
#define WBLOCKS  576
#define OUTHALF  7372800   // 16384*50*9
#define THRESH   6.2f

typedef _Float16 half8  __attribute__((ext_vector_type(8)));
typedef _Float16 half4v __attribute__((ext_vector_type(4)));
typedef __fp16   fp16x2 __attribute__((ext_vector_type(2)));
typedef __fp16   fp16x8 __attribute__((ext_vector_type(8)));
typedef float    f32x4  __attribute__((ext_vector_type(4)));

// ---- prep: W fp32 [9][50][240] -> f16 [9][64][256], zero padded in oc & k ----
__global__ __launch_bounds__(256)
void wprep_kernel(const float* __restrict__ W, _Float16* __restrict__ wks) {
    int idx = blockIdx.x * 256 + threadIdx.x;        // 0 .. 147455
    int k   = idx & 255;
    int ocp = (idx >> 8) & 63;
    int sec = idx >> 14;
    float v = 0.0f;
    if (ocp < NOC && k < KREAL)
        v = W[(size_t)(sec * NOC + ocp) * KREAL + k];
    wks[idx] = (_Float16)v;
}

// load 8 consecutive x floats -> half8 A-fragment (2x dwordx4 + 4x cvt_pkrtz)
__device__ __forceinline__ half8 load_a8(const float* __restrict__ p) {
    float4 a = *(const float4*)p;
    float4 b = *(const float4*)(p + 4);
    fp16x2 c0 = __builtin_amdgcn_cvt_pkrtz(a.x, a.y);
    fp16x2 c1 = __builtin_amdgcn_cvt_pkrtz(a.z, a.w);
    fp16x2 c2 = __builtin_amdgcn_cvt_pkrtz(b.x, b.y);
    fp16x2 c3 = __builtin_amdgcn_cvt_pkrtz(b.z, b.w);
    fp16x8 r;
    r[0] = c0[0]; r[1] = c0[1]; r[2] = c1[0]; r[3] = c1[1];
    r[4] = c2[0]; r[5] = c2[1]; r[6] = c3[0]; r[7] = c3[1];
    return __builtin_bit_cast(half8, r);
}

// ---- fused: no A-LDS, no staging barriers. Wave w owns sections {2w,2w+1}
//      (all 4 n-tiles) + section 8 n-tile w (perfect 288-MFMA balance).
//      A gathered straight from global fp32 x; B from L2-hot f16 wks. ----
__global__ __launch_bounds__(256, 3)
void fused2_kernel(const float* __restrict__ x,
                   const _Float16* __restrict__ wks,
                   float* __restrict__ out) {
    __shared__ float t[TB * 450];    // 28800 B: epilogue transpose only

    const int tid  = threadIdx.x;
    const int lane = tid & 63;
    const int w    = tid >> 6;
    const int l15  = lane & 15;
    const int quad = lane >> 4;
    const int b0   = blockIdx.x * TB;

    const float* __restrict__ ar = x + (size_t)(b0 + l15) * XROW; // A: m=l15

    half4v res[2][4];   // pooled maxima, sections 2w+si, 4 n-tiles (f16)
    half4v res8;        // section 8, n-tile w

    // ---- two full sections per wave ----
    #pragma unroll
    for (int si = 0; si < 2; ++si) {
        const int s = 2 * w + si;
        const _Float16* __restrict__ wp =
            wks + ((size_t)s * NOCP + l15) * KPAD + quad * 8;   // B: n=l15
        f32x4 acc[4][4] = {};
        #pragma unroll
        for (int kk = 0; kk < 8; ++kk) {
            half8 av[4], bv[4];
            #pragma unroll
            for (int h = 0; h < 4; ++h) {
                int off = s * 160 + h * 40 + kk * 32 + quad * 8;
                av[h] = load_a8(ar + off);
            }
            #pragma unroll
            for (int n = 0; n < 4; ++n)
                bv[n] = *(const half8*)(wp + n * 16 * KPAD + kk * 32);
            #pragma unroll
            for (int h = 0; h < 4; ++h)
                #pragma unroll
                for (int n = 0; n < 4; ++n)
                    acc[h][n] = __builtin_amdgcn_mfma_f32_16x16x32_f16(
                                    av[h], bv[n], acc[h][n], 0, 0, 0);
        }
        #pragma unroll
        for (int n = 0; n < 4; ++n) {
            half4v r;
            #pragma unroll
            for (int j = 0; j < 4; ++j)
                r[j] = (_Float16)fmaxf(fmaxf(acc[0][n][j], acc[1][n][j]),
                                       fmaxf(acc[2][n][j], acc[3][n][j]));
            res[si][n] = r;
        }
    }

    // ---- section 8, single n-tile (n = w) ----
    {
        const _Float16* __restrict__ wp =
            wks + ((size_t)8 * NOCP + w * 16 + l15) * KPAD + quad * 8;
        f32x4 acc[4] = {f32x4{}, f32x4{}, f32x4{}, f32x4{}};
        #pragma unroll
        for (int kk = 0; kk < 8; ++kk) {
            half8 bv = *(const half8*)(wp + kk * 32);
            #pragma unroll
            for (int h = 0; h < 4; ++h) {
                int off = 8 * 160 + h * 40 + kk * 32 + quad * 8;
                if (off > XROW - 8) off = XROW - 8;   // in-row; k>=240 hits W zero-pad
                half8 av = load_a8(ar + off);
                acc[h] = __builtin_amdgcn_mfma_f32_16x16x32_f16(
                             av, bv, acc[h], 0, 0, 0);
            }
        }
        half4v r;
        #pragma unroll
        for (int j = 0; j < 4; ++j)
            r[j] = (_Float16)fmaxf(fmaxf(acc[0][j], acc[1][j]),
                                   fmaxf(acc[2][j], acc[3][j]));
        res8 = r;
    }

    // ---- epilogue: transpose via LDS, coalesced float4 writes ----
    // D layout: col(oc part)=l15, row(batch)=quad*4+j
    #pragma unroll
    for (int si = 0; si < 2; ++si) {
        const int s = 2 * w + si;
        #pragma unroll
        for (int n = 0; n < 4; ++n) {
            const int oc = n * 16 + l15;
            if (oc < NOC) {
                #pragma unroll
                for (int j = 0; j < 4; ++j)
                    t[(quad * 4 + j) * 450 + oc * 9 + s] = (float)res[si][n][j];
            }
        }
    }
    {
        const int oc = w * 16 + l15;
        if (oc < NOC) {
            #pragma unroll
            for (int j = 0; j < 4; ++j)
                t[(quad * 4 + j) * 450 + oc * 9 + 8] = (float)res8[j];
        }
    }
    __syncthreads();

    const size_t ob4 = (size_t)blockIdx.x * (TB * 450 / 4);   // float4 units
    float4* __restrict__ o4 = (float4*)out;
    float4* __restrict__ s4 = (float4*)(out + OUTHALF);
    for (int i = tid; i < TB * 450 / 4; i += 256) {
        float4 v = ((const float4*)t)[i];
        o4[ob4 + i] = v;
        float4 sp;
        sp.x = (v.x > THRESH) ? 1.0f : 0.0f;
        sp.y = (v.y > THRESH) ? 1.0f : 0.0f;
        sp.z = (v.z > THRESH) ? 1.0f : 0.0f;
        sp.w = (v.w > THRESH) ? 1.0f : 0.0f;
        s4[ob4 + i] = sp;
    }
}

// ---- last-resort fallback: direct fp32 ----
__global__ __launch_bounds__(256)
void naive_kernel(const float* __restrict__ x, const float* __restrict__ W,
                  float* __restrict__ out) {
    size_t idx = (size_t)blockIdx.x * 256 + threadIdx.x;
    if (idx >= OUTHALF) return;
    int s  = (int)(idx % NSEC);
    int oc = (int)((idx / NSEC) % NOC);
    int b  = (int)(idx / (NSEC * NOC));
    const float* xb = x + (size_t)b * XROW + s * 160;
    const float* wv = W + (size_t)(s * NOC + oc) * KREAL;
    float best = -1e30f;
    for (int h0 = 0; h0 < 4; ++h0) {
        float acc = 0.0f;
        for (int k = 0; k < KREAL; ++k)
            acc += xb[h0 * 40 + k] * wv[k];
        best = fmaxf(best, acc);
    }
    out[idx] = best;
    out[OUTHALF + idx] = (best > THRESH) ? 1.0f : 0.0f;
}

extern "C" void kernel_launch(void* const* d_in, const int* in_sizes, int n_in,
                              void* d_out, int out_size, void* d_ws, size_t ws_size,
                              hipStream_t stream) {
    const float* x = (const float*)d_in[0];   // [16384,1,41,40]
    const float* W = (const float*)d_in[1];   // [9,50,1,6,40]
    float* out = (float*)d_out;               // pots(7372800) ++ spks(7372800)

    const size_t w_bytes = (size_t)WELEMS * sizeof(_Float16);   // 294912

    if (ws_size < w_bytes) {
        naive_kernel<<<(OUTHALF + 255) / 256, 256, 0, stream>>>(x, W, out);
        return;
    }

    _Float16* wks = (_Float16*)d_ws;
    wprep_kernel<<<WBLOCKS, 256, 0, stream>>>(W, wks);
    fused2_kernel<<<NBATCH / TB, 256, 0, stream>>>(x, wks, out);
}